// Round 16
// baseline (83.276 us; speedup 1.0000x reference)
//
#include <hip/hip_runtime.h>

// MFMA fragment layouts (gfx950, 16x16 family, verified m89):
//   A-frag (M16,K32): lane l holds A[row=l&15][k=(l>>4)*8+e], e=0..7
//   B-frag (K32,N16): lane l holds B[k=(l>>4)*8+e][col=l&15]
//   C/D:              col=l&15, row=(l>>4)*4+reg
// h subtiled: hS[jt][et][16][16] f16 (512 B subtiles).
// ds_read_b64_tr_b16 (verified v6/v8): lane addr = subtile + lg*128 + ll*8;
// elem e = subtile[lg*4+e][ll] — the K16 PV A-frag.
//
// v16: 1024-thr (16-wave) blocks, grid 256. launch_bounds(1024) caps total
// regs at 128 (= v8's measured 80 arch + 48 acc for the single-tile body) ->
// 16 waves/CU. Strips 0..15 one-per-wave; strips 16..18 split into 4
// j-quarters each (12 tasks -> waves 0..11) -> max wave load 24 tiles vs
// v13's 38. Quarter partials (per-lane m, lsum, acc[28]) merged via LDS +
// one __syncthreads using exact online-softmax algebra:
//   M = max m_q; out = (sum acc_q*2^(m_q-M)) / (sum lsum_q*2^(m_q-M)).
// Body = v13 components un-paired: compiler score reads, select, asm
// tr-reads, defer-max softmax (THR=8), single lgkmcnt(0), 7 PV MFMAs.

typedef _Float16 half8 __attribute__((ext_vector_type(8)));
typedef _Float16 half4 __attribute__((ext_vector_type(4)));
typedef float f32x4 __attribute__((ext_vector_type(4)));

constexpr int B_ = 256, N_ = 300, E_ = 100;
constexpr float NEGINF = -9e15f;
constexpr float PADV   = -3e38f;
constexpr float LOG2E  = 1.44269504088896f;

// LDS: hS [19][7][16][16] f16 (68096) | A16 [4][128] f16 (1024) @68096
//      | partials: 9 regions x 64 lanes x 30 f32 = 69120 B @69120
constexpr int PART_OFF  = 69120;
constexpr int LDS_BYTES = 69120 + 9 * 7680;   // 138240 <= 163840

#define TRD(dst, addr, off) \
  asm volatile("ds_read_b64_tr_b16 %0, %1 offset:" #off : "=v"(dst) : "v"(addr))
#define LGKM0 do { asm volatile("s_waitcnt lgkmcnt(0)" ::: "memory"); \
                   __builtin_amdgcn_sched_barrier(0); } while (0)

__global__ __launch_bounds__(1024)
void gat_flash14(const float* __restrict__ H, const int* __restrict__ ADJ,
                 const float* __restrict__ A, float* __restrict__ OUT) {
  extern __shared__ char smraw[];
  _Float16* hS   = (_Float16*)smraw;
  _Float16* A16  = (_Float16*)(smraw + 68096);
  float*    part = (float*)(smraw + PART_OFF);

  const int b = blockIdx.x;
  const int tid = threadIdx.x;
  const int w = tid >> 6, lane = tid & 63;
  const int lg = lane >> 4, ll = lane & 15;

  const float* Hb  = H + (size_t)b * (N_ * E_);
  const int*   AJb = ADJ + (size_t)b * (N_ * N_);

  // ---------------- stage h into subtiled LDS (zero-padded) ----------------
  for (int u = tid; u < 304 * 14; u += 1024) {
    const int j = u / 14, hr = u % 14;
    half8 v;
#pragma unroll
    for (int e = 0; e < 8; ++e) {
      const int d = hr * 8 + e;
      v[e] = (_Float16)((j < N_ && d < E_) ? Hb[j * E_ + d] : 0.f);
    }
    *(half8*)&hS[(((j >> 4) * 7 + (hr >> 1)) << 8) + ((j & 15) << 4) + ((hr & 1) << 3)] = v;
  }
  if (tid < 64) {
    const int k = tid >> 4, oct = tid & 15;
    half8 v;
#pragma unroll
    for (int e = 0; e < 8; ++e) {
      const int d = oct * 8 + e;
      v[e] = (_Float16)((d < E_) ? A[k * E_ + d] * LOG2E : 0.f);   // log2-domain
    }
    *(half8*)&A16[k * 128 + oct * 8] = v;
  }
  __syncthreads();

  const unsigned ldsbase = (unsigned)(size_t)(void*)hS;
  const unsigned trlane  = (unsigned)(ll * 8 + lg * 128);

  // ---- per-strip state (reused by main strip and quarter task) ----
  half8 g[3][4];
  half4 gt[4];
  float m, lsum;
  f32x4 acc[7];
  const int* ajrow = AJb;

  auto prep_strip = [&](int s) {
    const int irow = s * 16 + ll;
    const int irc  = irow < N_ ? irow : N_ - 1;
    ajrow = AJb + (size_t)irc * N_;
#pragma unroll
    for (int db = 0; db < 3; ++db) {
      const int doct = db * 4 + lg;
      const half8 hi = *(const half8*)&hS[((s * 7 + (doct >> 1)) << 8) + (ll << 4) + ((doct & 1) << 3)];
#pragma unroll
      for (int k = 0; k < 4; ++k)
        g[db][k] = hi * *(const half8*)&A16[k * 128 + doct * 8];
    }
    const half4 hit = *(const half4*)&hS[((s * 7 + 6) << 8) + (ll << 4) + lg * 4];
#pragma unroll
    for (int k = 0; k < 4; ++k)
      gt[k] = hit * *(const half4*)&A16[k * 128 + 96 + lg * 4];
    m = PADV; lsum = 0.f;
#pragma unroll
    for (int t = 0; t < 7; ++t) acc[t] = (f32x4){0.f, 0.f, 0.f, 0.f};
  };

  auto load_adj = [&](int jt) -> int4 {
    int jc = jt * 16 + lg * 4;
    if (jc > N_ - 4) jc = N_ - 4;
    return *(const int4*)(ajrow + jc);
  };

  auto tile_body = [&](int jt, int4 av, bool tail) {
    // ---- scores (compiler-scheduled LDS reads) ----
    f32x4 c0 = {0.f, 0.f, 0.f, 0.f}, c1 = c0, c2 = c0, c3 = c0;
#pragma unroll
    for (int db = 0; db < 3; ++db) {
      const int doct = db * 4 + lg;
      const half8 aj = *(const half8*)&hS[((jt * 7 + (doct >> 1)) << 8) + (ll << 4) + ((doct & 1) << 3)];
      c0 = __builtin_amdgcn_mfma_f32_16x16x32_f16(aj, g[db][0], c0, 0, 0, 0);
      c1 = __builtin_amdgcn_mfma_f32_16x16x32_f16(aj, g[db][1], c1, 0, 0, 0);
      c2 = __builtin_amdgcn_mfma_f32_16x16x32_f16(aj, g[db][2], c2, 0, 0, 0);
      c3 = __builtin_amdgcn_mfma_f32_16x16x32_f16(aj, g[db][3], c3, 0, 0, 0);
    }
    {
      const half4 ajt = *(const half4*)&hS[((jt * 7 + 6) << 8) + (ll << 4) + lg * 4];
      c0 = __builtin_amdgcn_mfma_f32_16x16x16f16(ajt, gt[0], c0, 0, 0, 0);
      c1 = __builtin_amdgcn_mfma_f32_16x16x16f16(ajt, gt[1], c1, 0, 0, 0);
      c2 = __builtin_amdgcn_mfma_f32_16x16x16f16(ajt, gt[2], c2, 0, 0, 0);
      c3 = __builtin_amdgcn_mfma_f32_16x16x16f16(ajt, gt[3], c3, 0, 0, 0);
    }
    // ---- select by adj + leaky-relu + mask ----
    const int va[4] = {av.x, av.y, av.z, av.w};
    float sv[4];
#pragma unroll
    for (int r = 0; r < 4; ++r) {
      const float e = (va[r] == 1) ? c0[r] : (va[r] == 2) ? c1[r]
                     : (va[r] == 3) ? c2[r] : c3[r];
      sv[r] = (va[r] == 0) ? NEGINF : fmaxf(e, 0.2f * e);
    }
    if (tail && lg == 3) { sv[0] = PADV; sv[1] = PADV; sv[2] = PADV; sv[3] = PADV; }

    // ---- PV h^T fragments (c-regs dead); latency covered by softmax ----
    const unsigned trb = ldsbase + (unsigned)(jt * 3584) + trlane;
    half4 tr[7];
    TRD(tr[0], trb, 0);    TRD(tr[1], trb, 512);  TRD(tr[2], trb, 1024);
    TRD(tr[3], trb, 1536); TRD(tr[4], trb, 2048); TRD(tr[5], trb, 2560);
    TRD(tr[6], trb, 3072);

    // ---- deferred online softmax (THR=8; P <= 2^8 in fp16) ----
    const float lmax = fmaxf(fmaxf(sv[0], sv[1]), fmaxf(sv[2], sv[3]));
    if (__any(lmax > m + 8.f)) {
      float tmax = fmaxf(lmax, __shfl_xor(lmax, 16));
      tmax = fmaxf(tmax, __shfl_xor(tmax, 32));
      const float nm = fmaxf(m, tmax);
      const float f = exp2f(m - nm);
      m = nm; lsum *= f;
#pragma unroll
      for (int t = 0; t < 7; ++t) {
        acc[t][0] *= f; acc[t][1] *= f; acc[t][2] *= f; acc[t][3] *= f;
      }
    }
    const float p0 = exp2f(sv[0] - m), p1 = exp2f(sv[1] - m);
    const float p2 = exp2f(sv[2] - m), p3 = exp2f(sv[3] - m);
    lsum += (p0 + p1) + (p2 + p3);
    half4 pb;
    pb[0] = (_Float16)p0; pb[1] = (_Float16)p1;
    pb[2] = (_Float16)p2; pb[3] = (_Float16)p3;

    LGKM0;   // rule #18: drain tr reads, fence MFMA hoisting
#pragma unroll
    for (int t = 0; t < 7; ++t)
      acc[t] = __builtin_amdgcn_mfma_f32_16x16x16f16(tr[t], pb, acc[t], 0, 0, 0);
  };

  auto store_rows = [&](int s) {
    lsum += __shfl_xor(lsum, 16);
    lsum += __shfl_xor(lsum, 32);
    const float rv = 1.f / lsum;
    const int irow = s * 16 + ll;
    if (irow < N_) {
      float* orow = OUT + ((size_t)b * N_ + irow) * E_;
#pragma unroll
      for (int t = 0; t < 7; ++t) {
        const int e0 = t * 16 + lg * 4;
        if (e0 < E_) {
          f32x4 o = acc[t];
          o[0] *= rv; o[1] *= rv; o[2] *= rv; o[3] *= rv;
          *(f32x4*)&orow[e0] = o;
        }
      }
    }
  };

  // ================= main strip: wave w owns strip w (0..15) ===============
  prep_strip(w);
  {
    int4 av = load_adj(0);
    for (int jt = 0; jt < 18; ++jt) {
      const int4 nv = load_adj(jt + 1);
      tile_body(jt, av, false);
      av = nv;
    }
    tile_body(18, av, true);
  }
  store_rows(w);

  // ================= quarter tasks: strips 16..18 x 4 j-quarters ===========
  if (w < 12) {
    const int t = w >> 2, q = w & 3;
    const int s2 = 16 + t;
    prep_strip(s2);
    const int j0 = q * 5;
    const int j1 = (q < 3) ? (j0 + 5) : 18;   // q3: tiles 15..17 + tail
    int4 av = load_adj(j0);
    for (int jt = j0; jt < j1; ++jt) {
      const int4 nv = load_adj(jt + 1);
      tile_body(jt, av, false);
      av = nv;
    }
    if (q == 3) tile_body(18, av, true);

    if (q) {   // write partial (per-lane 28 acc + m + lsum)
      float* dst = part + (size_t)(t * 3 + (q - 1)) * 1920 + lane * 30;
#pragma unroll
      for (int tt = 0; tt < 7; ++tt) {
        dst[4 * tt + 0] = acc[tt][0]; dst[4 * tt + 1] = acc[tt][1];
        dst[4 * tt + 2] = acc[tt][2]; dst[4 * tt + 3] = acc[tt][3];
      }
      dst[28] = m; dst[29] = lsum;
    }
  }
  __syncthreads();

  // ================= merge: q==0 waves combine 4 partials, store ===========
  if (w < 12 && (w & 3) == 0) {
    const int t = w >> 2;
#pragma unroll
    for (int q = 1; q <= 3; ++q) {
      const float* src = part + (size_t)(t * 3 + (q - 1)) * 1920 + lane * 30;
      const float mq = src[28], lq = src[29];
      const float M  = fmaxf(m, mq);
      const float f0 = exp2f(m - M), f1 = exp2f(mq - M);
      m = M;
      lsum = lsum * f0 + lq * f1;
#pragma unroll
      for (int tt = 0; tt < 7; ++tt) {
        acc[tt][0] = acc[tt][0] * f0 + src[4 * tt + 0] * f1;
        acc[tt][1] = acc[tt][1] * f0 + src[4 * tt + 1] * f1;
        acc[tt][2] = acc[tt][2] * f0 + src[4 * tt + 2] * f1;
        acc[tt][3] = acc[tt][3] * f0 + src[4 * tt + 3] * f1;
      }
    }
    store_rows(16 + t);
  }
}

extern "C" void kernel_launch(void* const* d_in, const int* in_sizes, int n_in,
                              void* d_out, int out_size, void* d_ws, size_t ws_size,
                              hipStream_t stream) {
  const float* H  = (const float*)d_in[0];
  const int*   AJ = (const int*)d_in[1];
  const float* A  = (const float*)d_in[2];
  float* OUT = (float*)d_out;

  (void)hipFuncSetAttribute(reinterpret_cast<const void*>(gat_flash14),
                            hipFuncAttributeMaxDynamicSharedMemorySize,
                            LDS_BYTES);
  gat_flash14<<<B_, 1024, LDS_BYTES, stream>>>(H, AJ, A, OUT);
}

// Round 18
// 67.733 us; speedup vs baseline: 1.2295x; 1.2295x over previous
//
#include <hip/hip_runtime.h>

// MFMA fragment layouts (gfx950, 16x16 family, verified m89):
//   A-frag (M16,K32): lane l holds A[row=l&15][k=(l>>4)*8+e], e=0..7
//   B-frag (K32,N16): lane l holds B[k=(l>>4)*8+e][col=l&15]
//   C/D:              col=l&15, row=(l>>4)*4+reg
// h subtiled: hS[jt][et][16][16] f16 (512 B subtiles).
// ds_read_b64_tr_b16 (verified v6/v8): lane addr = subtile + lg*128 + ll*8;
// elem e = subtile[lg*4+e][ll] — the K16 PV A-frag.
//
// v18 = v17 with the partial-region layout reverted to v16's VERIFIED one:
// region stride 64 lanes x 30 f32 (7680 B), dst = part + region*1920 +
// lane*30. (v17's "swizzle" lane*128 ^ ((lane&7)<<4) shifted the base up to
// +112 B inside a 128-B slot and then wrote 120 B -> overflowed into the
// next lane's slot -> absmax 1614.) The 30-word stride is naturally
// bank-spread; these writes occur 11x per block (negligible).
// Flattened balance (v17): wave w owns units [30w, 30(w+1)) of the 19x19
// (strip,tile) space; tail segment (j0>0) writes partial to region[w-1];
// head segment (j1<19) merges region[w] after ONE barrier with the exact
// online-softmax combine (verified v16); whole strips store directly.
// Critical path 38 -> 30-31 tiles. Geometry: 768 thr / 12 waves / grid 256,
// NO reg bound (84+48 spill-free).

typedef _Float16 half8 __attribute__((ext_vector_type(8)));
typedef _Float16 half4 __attribute__((ext_vector_type(4)));
typedef float f32x4 __attribute__((ext_vector_type(4)));

constexpr int B_ = 256, N_ = 300, E_ = 100;
constexpr float NEGINF = -9e15f;
constexpr float PADV   = -3e38f;
constexpr float LOG2E  = 1.44269504088896f;

// LDS: hS [19][7][16][16] f16 (68096) | A16 [4][128] f16 @68096 (1024)
//      | 11 partial regions x 64 lanes x 30 f32 = 84480 B @69120
constexpr int PART_OFF  = 69120;
constexpr int LDS_BYTES = 69120 + 11 * 7680;   // 153600 <= 163840

#define TRD(dst, addr, off) \
  asm volatile("ds_read_b64_tr_b16 %0, %1 offset:" #off : "=v"(dst) : "v"(addr))
#define LGKM0 do { asm volatile("s_waitcnt lgkmcnt(0)" ::: "memory"); \
                   __builtin_amdgcn_sched_barrier(0); } while (0)

__global__ __launch_bounds__(768)
void gat_flash16(const float* __restrict__ H, const int* __restrict__ ADJ,
                 const float* __restrict__ A, float* __restrict__ OUT) {
  extern __shared__ char smraw[];
  _Float16* hS   = (_Float16*)smraw;
  _Float16* A16  = (_Float16*)(smraw + 68096);
  float*    part = (float*)(smraw + PART_OFF);

  const int b = blockIdx.x;
  const int tid = threadIdx.x;
  const int w = tid >> 6, lane = tid & 63;
  const int lg = lane >> 4, ll = lane & 15;

  const float* Hb  = H + (size_t)b * (N_ * E_);
  const int*   AJb = ADJ + (size_t)b * (N_ * N_);

  // ---------------- stage h into subtiled LDS (zero-padded) ----------------
  for (int u = tid; u < 304 * 14; u += 768) {
    const int j = u / 14, hr = u % 14;
    half8 v;
#pragma unroll
    for (int e = 0; e < 8; ++e) {
      const int d = hr * 8 + e;
      v[e] = (_Float16)((j < N_ && d < E_) ? Hb[j * E_ + d] : 0.f);
    }
    *(half8*)&hS[(((j >> 4) * 7 + (hr >> 1)) << 8) + ((j & 15) << 4) + ((hr & 1) << 3)] = v;
  }
  if (tid < 64) {
    const int k = tid >> 4, oct = tid & 15;
    half8 v;
#pragma unroll
    for (int e = 0; e < 8; ++e) {
      const int d = oct * 8 + e;
      v[e] = (_Float16)((d < E_) ? A[k * E_ + d] * LOG2E : 0.f);   // log2-domain
    }
    *(half8*)&A16[k * 128 + oct * 8] = v;
  }
  __syncthreads();

  const unsigned ldsbase = (unsigned)(size_t)(void*)hS;
  const unsigned trlane  = (unsigned)(ll * 8 + lg * 128);

  half8 g[3][4];
  half4 gt[4];
  float m, lsum;
  f32x4 acc[7];
  const int* ajrow = AJb;

  auto prep_strip = [&](int s) {
    const int irow = s * 16 + ll;
    const int irc  = irow < N_ ? irow : N_ - 1;
    ajrow = AJb + (size_t)irc * N_;
#pragma unroll
    for (int db = 0; db < 3; ++db) {
      const int doct = db * 4 + lg;
      const half8 hi = *(const half8*)&hS[((s * 7 + (doct >> 1)) << 8) + (ll << 4) + ((doct & 1) << 3)];
#pragma unroll
      for (int k = 0; k < 4; ++k)
        g[db][k] = hi * *(const half8*)&A16[k * 128 + doct * 8];
    }
    const half4 hit = *(const half4*)&hS[((s * 7 + 6) << 8) + (ll << 4) + lg * 4];
#pragma unroll
    for (int k = 0; k < 4; ++k)
      gt[k] = hit * *(const half4*)&A16[k * 128 + 96 + lg * 4];
    m = PADV; lsum = 0.f;
#pragma unroll
    for (int t = 0; t < 7; ++t) acc[t] = (f32x4){0.f, 0.f, 0.f, 0.f};
  };

  auto load_adj = [&](int jt) -> int4 {
    int jc = jt * 16 + lg * 4;
    if (jc > N_ - 4) jc = N_ - 4;
    return *(const int4*)(ajrow + jc);
  };

  auto tile_body = [&](int jt, int4 av, bool tail) {
    f32x4 c0 = {0.f, 0.f, 0.f, 0.f}, c1 = c0, c2 = c0, c3 = c0;
#pragma unroll
    for (int db = 0; db < 3; ++db) {
      const int doct = db * 4 + lg;
      const half8 aj = *(const half8*)&hS[((jt * 7 + (doct >> 1)) << 8) + (ll << 4) + ((doct & 1) << 3)];
      c0 = __builtin_amdgcn_mfma_f32_16x16x32_f16(aj, g[db][0], c0, 0, 0, 0);
      c1 = __builtin_amdgcn_mfma_f32_16x16x32_f16(aj, g[db][1], c1, 0, 0, 0);
      c2 = __builtin_amdgcn_mfma_f32_16x16x32_f16(aj, g[db][2], c2, 0, 0, 0);
      c3 = __builtin_amdgcn_mfma_f32_16x16x32_f16(aj, g[db][3], c3, 0, 0, 0);
    }
    {
      const half4 ajt = *(const half4*)&hS[((jt * 7 + 6) << 8) + (ll << 4) + lg * 4];
      c0 = __builtin_amdgcn_mfma_f32_16x16x16f16(ajt, gt[0], c0, 0, 0, 0);
      c1 = __builtin_amdgcn_mfma_f32_16x16x16f16(ajt, gt[1], c1, 0, 0, 0);
      c2 = __builtin_amdgcn_mfma_f32_16x16x16f16(ajt, gt[2], c2, 0, 0, 0);
      c3 = __builtin_amdgcn_mfma_f32_16x16x16f16(ajt, gt[3], c3, 0, 0, 0);
    }
    const int va[4] = {av.x, av.y, av.z, av.w};
    float sv[4];
#pragma unroll
    for (int r = 0; r < 4; ++r) {
      const float e = (va[r] == 1) ? c0[r] : (va[r] == 2) ? c1[r]
                     : (va[r] == 3) ? c2[r] : c3[r];
      sv[r] = (va[r] == 0) ? NEGINF : fmaxf(e, 0.2f * e);
    }
    if (tail && lg == 3) { sv[0] = PADV; sv[1] = PADV; sv[2] = PADV; sv[3] = PADV; }

    const unsigned trb = ldsbase + (unsigned)(jt * 3584) + trlane;
    half4 tr[7];
    TRD(tr[0], trb, 0);    TRD(tr[1], trb, 512);  TRD(tr[2], trb, 1024);
    TRD(tr[3], trb, 1536); TRD(tr[4], trb, 2048); TRD(tr[5], trb, 2560);
    TRD(tr[6], trb, 3072);

    const float lmax = fmaxf(fmaxf(sv[0], sv[1]), fmaxf(sv[2], sv[3]));
    if (__any(lmax > m + 8.f)) {
      float tmax = fmaxf(lmax, __shfl_xor(lmax, 16));
      tmax = fmaxf(tmax, __shfl_xor(tmax, 32));
      const float nm = fmaxf(m, tmax);
      const float f = exp2f(m - nm);
      m = nm; lsum *= f;
#pragma unroll
      for (int t = 0; t < 7; ++t) {
        acc[t][0] *= f; acc[t][1] *= f; acc[t][2] *= f; acc[t][3] *= f;
      }
    }
    const float p0 = exp2f(sv[0] - m), p1 = exp2f(sv[1] - m);
    const float p2 = exp2f(sv[2] - m), p3 = exp2f(sv[3] - m);
    lsum += (p0 + p1) + (p2 + p3);
    half4 pb;
    pb[0] = (_Float16)p0; pb[1] = (_Float16)p1;
    pb[2] = (_Float16)p2; pb[3] = (_Float16)p3;

    LGKM0;   // rule #18
#pragma unroll
    for (int t = 0; t < 7; ++t)
      acc[t] = __builtin_amdgcn_mfma_f32_16x16x16f16(tr[t], pb, acc[t], 0, 0, 0);
  };

  auto store_rows = [&](int s) {
    float ls = lsum;
    ls += __shfl_xor(ls, 16);
    ls += __shfl_xor(ls, 32);
    const float rv = 1.f / ls;
    const int irow = s * 16 + ll;
    if (irow < N_) {
      float* orow = OUT + ((size_t)b * N_ + irow) * E_;
#pragma unroll
      for (int t = 0; t < 7; ++t) {
        const int e0 = t * 16 + lg * 4;
        if (e0 < E_) {
          f32x4 o = acc[t];
          o[0] *= rv; o[1] *= rv; o[2] *= rv; o[3] *= rv;
          *(f32x4*)&orow[e0] = o;
        }
      }
    }
  };

  // ============ flattened tile-space: wave w owns units [30w, u1) ==========
  int u = 30 * w;
  const int u1 = (w == 11) ? 361 : (u + 30);
  bool held = false;
  int s_held = 0;

  while (u < u1) {
    const int s  = u / 19;
    const int j0 = u - 19 * s;
    const int j1 = (19 < j0 + (u1 - u)) ? 19 : (j0 + (u1 - u));
    prep_strip(s);
    int4 av = load_adj(j0);
    for (int jt = j0; jt < j1; ++jt) {
      const int4 nv = (jt + 1 < j1) ? load_adj(jt + 1) : av;
      tile_body(jt, av, jt == 18);
      av = nv;
    }
    if (j0 > 0) {
      // tail segment of a split strip -> write partial to region[w-1]
      float* dst = part + (size_t)(w - 1) * 1920 + lane * 30;
#pragma unroll
      for (int t = 0; t < 7; ++t) {
        dst[4 * t + 0] = acc[t][0]; dst[4 * t + 1] = acc[t][1];
        dst[4 * t + 2] = acc[t][2]; dst[4 * t + 3] = acc[t][3];
      }
      dst[28] = m; dst[29] = lsum;
    } else if (j1 < 19) {
      held = true; s_held = s;       // head segment: merge after barrier
    } else {
      store_rows(s);                 // whole strip
    }
    u += j1 - j0;
  }

  __syncthreads();

  if (held) {
    // merge region[w] (written by wave w+1's tail segment of s_held)
    const float* src = part + (size_t)w * 1920 + lane * 30;
    const float mq = src[28], lq = src[29];
    const float M  = fmaxf(m, mq);
    const float f0 = exp2f(m - M), f1 = exp2f(mq - M);
    m = M;
    lsum = lsum * f0 + lq * f1;
#pragma unroll
    for (int t = 0; t < 7; ++t) {
      acc[t][0] = acc[t][0] * f0 + src[4 * t + 0] * f1;
      acc[t][1] = acc[t][1] * f0 + src[4 * t + 1] * f1;
      acc[t][2] = acc[t][2] * f0 + src[4 * t + 2] * f1;
      acc[t][3] = acc[t][3] * f0 + src[4 * t + 3] * f1;
    }
    store_rows(s_held);
  }
}

extern "C" void kernel_launch(void* const* d_in, const int* in_sizes, int n_in,
                              void* d_out, int out_size, void* d_ws, size_t ws_size,
                              hipStream_t stream) {
  const float* H  = (const float*)d_in[0];
  const int*   AJ = (const int*)d_in[1];
  const float* A  = (const float*)d_in[2];
  float* OUT = (float*)d_out;

  (void)hipFuncSetAttribute(reinterpret_cast<const void*>(gat_flash16),
                            hipFuncAttributeMaxDynamicSharedMemorySize,
                            LDS_BYTES);
  gat_flash16<<<B_, 768, LDS_BYTES, stream>>>(H, AJ, A, OUT);
}